// Round 1
// baseline (83.264 us; speedup 1.0000x reference)
//
#include <hip/hip_runtime.h>
#include <hip/hip_bf16.h>
#include <math.h>

#define N_IMG 8192
#define M_TXT 8192
#define DIMK  256
#define BT    128    // output tile (BT x BT)
#define BK    32     // K-step

typedef short bf16x8 __attribute__((ext_vector_type(8)));
typedef float f32x16 __attribute__((ext_vector_type(16)));

__device__ inline void gload_lds16(const void* g, void* l) {
    __builtin_amdgcn_global_load_lds(
        (const __attribute__((address_space(1))) unsigned int*)g,
        (__attribute__((address_space(3))) unsigned int*)l,
        16, 0, 0);
}

// RNE fp32 -> bf16 (inputs finite, |x|<=1 -> no NaN handling needed)
__device__ inline unsigned short f2bf(float x) {
    unsigned u = __float_as_uint(x);
    u += 0x7FFFu + ((u >> 16) & 1u);
    return (unsigned short)(u >> 16);
}

// fp32 -> bf16 with the LDS anti-bank-conflict rotation PRE-APPLIED at the
// global level (global_load_lds writes LDS linearly -> permutation must live
// in the source). K-blocks of 32 elems = 4 chunks of 8 bf16; physical chunk j
// of row r holds logical chunk (j - (r>>1)) & 3. The 32x32x16 fragment reads
// use slot = (chunk + (row>>1)) & 3: every aligned 8-lane group then hits 8
// distinct 16B quads -> conflict-free ds_read_b128 (same property as the
// previous 16x16 reader; verified 0 conflicts on HW). Block 0 also zeroes
// the accumulators.
__global__ void convert_swz(const float* __restrict__ srcA,
                            const float* __restrict__ srcB,
                            unsigned short* __restrict__ dstA,
                            unsigned short* __restrict__ dstB,
                            double* __restrict__ accums) {
    if (blockIdx.x == 0) {
#pragma unroll
        for (int s = 0; s < 8; ++s) accums[threadIdx.x * 8 + s] = 0.0;
    }
    int q = blockIdx.x * blockDim.x + threadIdx.x;
    const int per = N_IMG * (DIMK / 8);
    const float* src; unsigned short* dst; int qq = q;
    if (q < per) { src = srcA; dst = dstA; }
    else         { src = srcB; dst = dstB; qq = q - per; }
    int r  = qq >> 5, jj = qq & 31;          // 32 chunks per row
    int kb = jj >> 2, j = jj & 3;            // K-block (32 elems), chunk in block
    int c  = (j - (r >> 1)) & 3;             // logical chunk stored here
    const float4* s = (const float4*)(src + (size_t)r * DIMK + kb * 32 + c * 8);
    float4 a = s[0], b = s[1];
    uint4 w;
    w.x = (unsigned)f2bf(a.x) | ((unsigned)f2bf(a.y) << 16);
    w.y = (unsigned)f2bf(a.z) | ((unsigned)f2bf(a.w) << 16);
    w.z = (unsigned)f2bf(b.x) | ((unsigned)f2bf(b.y) << 16);
    w.w = (unsigned)f2bf(b.z) | ((unsigned)f2bf(b.w) << 16);
    ((uint4*)dst)[qq] = w;
}

// Fused NT GEMM (img @ text^T) + multi-similarity masked reduction.
// 128x128 tile, 4 waves (2Mx2N), 32x32x16 MFMA (half the MFMA issue slots of
// 16x16x32, 2495 vs 2075 TF pipe ceiling), BK=32, double-buffered LDS (32 KB)
// -> target 4 blocks/CU so epilogue VALU of one block overlaps MFMA of
// co-resident blocks (m114 mechanism).
// Epilogue restructured to cut VALU issue: counts ride the SALU pipe via
// ballot+popcount (wave-uniform), and the rare positive-pair path (eq density
// = 1/100 -> P(any lane) ~ 27% per element) sits behind a wave-uniform branch.
__launch_bounds__(256, 4)
__global__ void msloss_gemm(const unsigned short* __restrict__ Abf,
                            const unsigned short* __restrict__ Bbf,
                            const int* __restrict__ rowLab,
                            const int* __restrict__ colLab,
                            double* __restrict__ accums) {
    __shared__ __align__(16) unsigned short As[2][BT * BK];   // 8 KB each
    __shared__ __align__(16) unsigned short Bs[2][BT * BK];

    int tid  = threadIdx.x;
    int wave = tid >> 6, lane = tid & 63;
    int l31  = lane & 31, hi = lane >> 5;
    int wrow = (wave >> 1) * 64, wcol = (wave & 1) * 64;

    // bijective XCD swizzle (4096 blocks, 8 XCDs); within an XCD consecutive
    // blocks walk J at fixed I -> A-panel L2 reuse.
    int swz = (blockIdx.x & 7) * 512 + (blockIdx.x >> 3);
    int tileRow = (swz >> 6) * BT;
    int tileCol = (swz & 63) * BT;

    auto STAGE = [&](int sel, int k0) {
#pragma unroll
        for (int i = 0; i < 2; ++i) {
            int p = wave * 128 + i * 64 + lane;      // chunk id 0..511
            int r = p >> 2, j = p & 3;
            gload_lds16(Abf + (size_t)(tileRow + r) * DIMK + k0 + j * 8,
                        &As[sel][(wave * 128 + i * 64) * 8]);
        }
#pragma unroll
        for (int i = 0; i < 2; ++i) {
            int p = wave * 128 + i * 64 + lane;
            int r = p >> 2, j = p & 3;
            gload_lds16(Bbf + (size_t)(tileCol + r) * DIMK + k0 + j * 8,
                        &Bs[sel][(wave * 128 + i * 64) * 8]);
        }
    };

    f32x16 acc[2][2] = {};

    STAGE(0, 0);
    asm volatile("s_waitcnt vmcnt(0)" ::: "memory");
    __builtin_amdgcn_s_barrier();
    __builtin_amdgcn_sched_barrier(0);

    int rot = (l31 >> 1) & 3;   // (full row >> 1) & 3 reduces to this (tile bases % 4 == 0)

#pragma unroll 1
    for (int t = 0; t < DIMK / BK; ++t) {
        if (t < DIMK / BK - 1) {
            STAGE((t + 1) & 1, (t + 1) * BK);        // 4 loads/lane in flight
            asm volatile("s_waitcnt vmcnt(4)" ::: "memory");  // wait for PREVIOUS stage
        } else {
            asm volatile("s_waitcnt vmcnt(0)" ::: "memory");
        }
        __builtin_amdgcn_s_barrier();                // all waves' stage done
        __builtin_amdgcn_sched_barrier(0);

        const unsigned short* as = As[t & 1];
        const unsigned short* bs = Bs[t & 1];
        // 32x32x16 A-frag: lane -> row = l31, k = hi*8..hi*8+7 (per K16 sub-step)
        // logical chunk (k/8) within the K32 block = ks*2 + hi; physical slot
        // adds the pre-applied rotation.
        bf16x8 a[2][2], b[2][2];
#pragma unroll
        for (int mi = 0; mi < 2; ++mi)
#pragma unroll
            for (int ks = 0; ks < 2; ++ks) {
                int slot = (ks * 2 + hi + rot) & 3;
                a[mi][ks] = *(const bf16x8*)(as + (wrow + mi * 32 + l31) * BK + slot * 8);
            }
#pragma unroll
        for (int ni = 0; ni < 2; ++ni)
#pragma unroll
            for (int ks = 0; ks < 2; ++ks) {
                int slot = (ks * 2 + hi + rot) & 3;
                b[ni][ks] = *(const bf16x8*)(bs + (wcol + ni * 32 + l31) * BK + slot * 8);
            }

        __builtin_amdgcn_s_setprio(1);
#pragma unroll
        for (int ks = 0; ks < 2; ++ks)
#pragma unroll
            for (int mi = 0; mi < 2; ++mi)
#pragma unroll
                for (int ni = 0; ni < 2; ++ni)
                    acc[mi][ni] = __builtin_amdgcn_mfma_f32_32x32x16_bf16(
                        a[mi][ks], b[ni][ks], acc[mi][ni], 0, 0, 0);
        __builtin_amdgcn_s_setprio(0);

        asm volatile("s_waitcnt lgkmcnt(0)" ::: "memory");   // reads of buf done
        __builtin_amdgcn_sched_barrier(0);
        __builtin_amdgcn_s_barrier();
    }

    // ---- fused epilogue ----
    // C/D layout (32x32): col = lane&31, row = (reg&3) + 8*(reg>>2) + 4*(lane>>5)
    int tr = tileRow + wrow, tc = tileCol + wcol;
    int cl0 = colLab[tc + l31];
    int cl1 = colLab[tc + 32 + l31];

    const float CNEG = 57.707801635558536f;    //  40 * log2(e)
    const float DNEG = -28.853900817779268f;   // -20 * log2(e)
    const float CPOS = -2.8853900817779268f;   //  -2 * log2(e)
    const float DPOS = 1.4426950408889634f;    //      log2(e)

    float ps = 0.f, nsa = 0.f, nsc = 0.f;
    int posc = 0, pec = 0;                     // wave-uniform (SALU) counters

#pragma unroll
    for (int mi = 0; mi < 2; ++mi) {
        int4 rl4[4];
#pragma unroll
        for (int g = 0; g < 4; ++g)
            rl4[g] = *(const int4*)(rowLab + tr + mi * 32 + g * 8 + 4 * hi);
#pragma unroll
        for (int g = 0; g < 4; ++g) {
            int lab[4] = {rl4[g].x, rl4[g].y, rl4[g].z, rl4[g].w};
#pragma unroll
            for (int j = 0; j < 4; ++j) {
                int myrl = lab[j];
#pragma unroll
                for (int ni = 0; ni < 2; ++ni) {
                    float v  = acc[mi][ni][g * 4 + j];
                    bool pos = v > 0.f;
                    bool eq  = myrl == (ni ? cl1 : cl0);
                    float en = exp2f(fmaf(v, CNEG, DNEG));   // neg-path exp, always
                    nsa += pos ? en : 0.f;                   // includes eq terms; fixed below
                    posc += (int)__popcll(__ballot(pos));    // SALU: s_bcnt1 + s_add
                    unsigned long long mpe = __ballot(pos && eq);
                    if (mpe) {                               // wave-uniform, ~27% taken
                        bool pe  = pos && eq;
                        float ep = exp2f(fmaf(v, CPOS, DPOS));
                        ps  += pe ? ep : 0.f;
                        nsc += pe ? en : 0.f;                // remove from neg sum
                        pec += (int)__popcll(mpe);
                    }
                }
            }
        }
    }
    float ns = nsa - nsc;
    // wave reduce (64 lanes) — only the two float sums; counts are uniform
#pragma unroll
    for (int off = 32; off > 0; off >>= 1) {
        ps += __shfl_down(ps, off, 64);
        ns += __shfl_down(ns, off, 64);
    }
    if (lane == 0) {
        double* s = accums + ((((unsigned)blockIdx.x << 2) | (unsigned)wave) & 255u) * 8;
        atomicAdd(s + 0, (double)ps);
        atomicAdd(s + 1, (double)ns);
        atomicAdd((unsigned long long*)(s + 2), (unsigned long long)pec);
        atomicAdd((unsigned long long*)(s + 3), (unsigned long long)(posc - pec));
    }
}

__global__ void finalize_loss(const double* __restrict__ accums,
                              float* __restrict__ out) {
    int lane = threadIdx.x;
    double ps = 0, ns = 0, pc = 0, nc = 0;
#pragma unroll
    for (int s = lane; s < 256; s += 64) {
        ps += accums[s * 8 + 0];
        ns += accums[s * 8 + 1];
        pc += (double)((const unsigned long long*)accums)[s * 8 + 2];
        nc += (double)((const unsigned long long*)accums)[s * 8 + 3];
    }
#pragma unroll
    for (int off = 32; off > 0; off >>= 1) {
        ps += __shfl_down(ps, off, 64);
        ns += __shfl_down(ns, off, 64);
        pc += __shfl_down(pc, off, 64);
        nc += __shfl_down(nc, off, 64);
    }
    if (lane == 0) {
        double pl = (pc > 0.0) ? log1p(ps) / (2.0 * pc)  : 0.0;
        double nl = (nc > 0.0) ? log1p(ns) / (40.0 * nc) : 0.0;
        out[0] = (float)(pl + nl);
    }
}

extern "C" void kernel_launch(void* const* d_in, const int* in_sizes, int n_in,
                              void* d_out, int out_size, void* d_ws, size_t ws_size,
                              hipStream_t stream) {
    (void)in_sizes; (void)n_in; (void)out_size;
    const float* img    = (const float*)d_in[0];
    const float* txt    = (const float*)d_in[1];
    const int*   gt_pre = (const int*)d_in[2];
    const int*   gt_map = (const int*)d_in[3];
    float* out = (float*)d_out;

    const size_t ACC_BYTES = 256 * 8 * sizeof(double);   // 16 KB, 64B slots
    const size_t MAT_BYTES = (size_t)N_IMG * DIMK * 2;   // 4 MB each
    if (ws_size < ACC_BYTES + 2 * MAT_BYTES) return;

    double*         accums = (double*)d_ws;
    unsigned short* Abf = (unsigned short*)((char*)d_ws + ACC_BYTES);
    unsigned short* Bbf = (unsigned short*)((char*)d_ws + ACC_BYTES + MAT_BYTES);

    int nchunks = 2 * N_IMG * (DIMK / 8);
    convert_swz<<<nchunks / 256, 256, 0, stream>>>(img, txt, Abf, Bbf, accums);
    msloss_gemm<<<(N_IMG / BT) * (M_TXT / BT), 256, 0, stream>>>(Abf, Bbf, gt_pre, gt_map, accums);
    finalize_loss<<<1, 64, 0, stream>>>(accums, out);
}

// Round 2
// 78.898 us; speedup vs baseline: 1.0553x; 1.0553x over previous
//
#include <hip/hip_runtime.h>
#include <hip/hip_bf16.h>
#include <math.h>

#define N_IMG 8192
#define M_TXT 8192
#define DIMK  256
#define BT    128    // output tile (BT x BT)
#define BK    32     // K-step

typedef short bf16x8 __attribute__((ext_vector_type(8)));
typedef float f32x4  __attribute__((ext_vector_type(4)));

__device__ inline void gload_lds16(const void* g, void* l) {
    __builtin_amdgcn_global_load_lds(
        (const __attribute__((address_space(1))) unsigned int*)g,
        (__attribute__((address_space(3))) unsigned int*)l,
        16, 0, 0);
}

// RNE fp32 -> bf16 (inputs finite, |x|<=1 -> no NaN handling needed)
__device__ inline unsigned short f2bf(float x) {
    unsigned u = __float_as_uint(x);
    u += 0x7FFFu + ((u >> 16) & 1u);
    return (unsigned short)(u >> 16);
}

// fp32 -> bf16 with the LDS anti-bank-conflict rotation PRE-APPLIED at the
// global level (global_load_lds writes LDS linearly -> permutation must live
// in the source). K-blocks of 32 elems = 4 chunks of 8 bf16; physical chunk j
// of row r holds logical chunk (j - (r>>1)) & 3. Read side uses slot
// (kg + (r16>>1)) & 3 with kg = lane>>4: HW-verified 0 conflicts (the slot
// offset MUST vary at lane>>4 granularity — a lane>>5-only variant measured
// 4.19M conflict cycles in round 1). Block 0 also zeroes the accumulators.
__global__ void convert_swz(const float* __restrict__ srcA,
                            const float* __restrict__ srcB,
                            unsigned short* __restrict__ dstA,
                            unsigned short* __restrict__ dstB,
                            double* __restrict__ accums) {
    if (blockIdx.x == 0) {
#pragma unroll
        for (int s = 0; s < 8; ++s) accums[threadIdx.x * 8 + s] = 0.0;
    }
    int q = blockIdx.x * blockDim.x + threadIdx.x;
    const int per = N_IMG * (DIMK / 8);
    const float* src; unsigned short* dst; int qq = q;
    if (q < per) { src = srcA; dst = dstA; }
    else         { src = srcB; dst = dstB; qq = q - per; }
    int r  = qq >> 5, jj = qq & 31;          // 32 chunks per row
    int kb = jj >> 2, j = jj & 3;            // K-block (32 elems), chunk in block
    int c  = (j - (r >> 1)) & 3;             // logical chunk stored here
    const float4* s = (const float4*)(src + (size_t)r * DIMK + kb * 32 + c * 8);
    float4 a = s[0], b = s[1];
    uint4 w;
    w.x = (unsigned)f2bf(a.x) | ((unsigned)f2bf(a.y) << 16);
    w.y = (unsigned)f2bf(a.z) | ((unsigned)f2bf(a.w) << 16);
    w.z = (unsigned)f2bf(b.x) | ((unsigned)f2bf(b.y) << 16);
    w.w = (unsigned)f2bf(b.z) | ((unsigned)f2bf(b.w) << 16);
    ((uint4*)dst)[qq] = w;
}

// Fused NT GEMM (img @ text^T) + multi-similarity masked reduction.
// 128x128 tile, 4 waves (2Mx2N), 16x16x32 MFMA (proven conflict-free LDS
// pattern), BK=32, TRIPLE-buffered LDS (48 KB, 3 blocks/CU):
//   - writer targets the buffer last read 2 iterations ago -> ONE barrier per
//     K-step, no explicit lgkmcnt(0) drain (a wave passes barrier t+1 only
//     after its iter-t MFMAs executed, whose compiler lgkm waits cover the
//     iter-t ds_reads; the next write to that buffer is issued after that
//     barrier across all waves).
//   - K-loop fully unrolled: buffer indices / k0 / slot are compile-time,
//     stage addresses fold into instruction offsets -> minimal loop VALU.
// Counts ride the SALU pipe (ballot+popcount); labels preloaded before the
// loop (drained by iter-0's vmcnt(4)).
__launch_bounds__(256, 3)
__global__ void msloss_gemm(const unsigned short* __restrict__ Abf,
                            const unsigned short* __restrict__ Bbf,
                            const int* __restrict__ rowLab,
                            const int* __restrict__ colLab,
                            double* __restrict__ accums) {
    __shared__ __align__(16) unsigned short As[3][BT * BK];   // 8 KB each
    __shared__ __align__(16) unsigned short Bs[3][BT * BK];

    int tid  = threadIdx.x;
    int wave = tid >> 6, lane = tid & 63;
    int r16  = lane & 15, kg = lane >> 4;
    int wrow = (wave >> 1) * 64, wcol = (wave & 1) * 64;

    // bijective XCD swizzle (4096 blocks, 8 XCDs); within an XCD consecutive
    // blocks walk J at fixed I -> A-panel L2 reuse.
    int swz = (blockIdx.x & 7) * 512 + (blockIdx.x >> 3);
    int tileRow = (swz >> 6) * BT;
    int tileCol = (swz & 63) * BT;

    // Preload labels into registers; these 8 loads complete at the first
    // in-loop vmcnt(4) (in-order vmcnt retirement), hidden under staging.
    int tr = tileRow + wrow, tc = tileCol + wcol;
    int4 rl4[4]; int mycl[4];
#pragma unroll
    for (int m = 0; m < 4; ++m)
        rl4[m] = *(const int4*)(rowLab + tr + m * 16 + kg * 4);
#pragma unroll
    for (int n = 0; n < 4; ++n)
        mycl[n] = colLab[tc + n * 16 + r16];

    auto STAGE = [&](int sel, int k0) {
#pragma unroll
        for (int i = 0; i < 2; ++i) {
            int p = wave * 128 + i * 64 + lane;      // chunk id 0..511
            int r = p >> 2, j = p & 3;
            gload_lds16(Abf + (size_t)(tileRow + r) * DIMK + k0 + j * 8,
                        &As[sel][(wave * 128 + i * 64) * 8]);
        }
#pragma unroll
        for (int i = 0; i < 2; ++i) {
            int p = wave * 128 + i * 64 + lane;
            int r = p >> 2, j = p & 3;
            gload_lds16(Bbf + (size_t)(tileCol + r) * DIMK + k0 + j * 8,
                        &Bs[sel][(wave * 128 + i * 64) * 8]);
        }
    };

    f32x4 acc[4][4] = {};
    int slot = ((r16 >> 1) + kg) & 3;

    STAGE(0, 0);                                     // buf0 in flight

#pragma unroll 8
    for (int t = 0; t < DIMK / BK; ++t) {
        if (t < DIMK / BK - 1) {
            STAGE((t + 1) % 3, (t + 1) * BK);        // 4 loads/lane in flight
            // wait until only the just-issued 4 remain -> stage t (and, at
            // t==0, the label loads) complete.
            asm volatile("s_waitcnt vmcnt(4)" ::: "memory");
        } else {
            asm volatile("s_waitcnt vmcnt(0)" ::: "memory");
        }
        __builtin_amdgcn_s_barrier();                // all waves' stage t done
        __builtin_amdgcn_sched_barrier(0);

        const unsigned short* as = As[t % 3];
        const unsigned short* bs = Bs[t % 3];
        bf16x8 a[4], b[4];
#pragma unroll
        for (int m = 0; m < 4; ++m)
            a[m] = *(const bf16x8*)(as + (wrow + m * 16 + r16) * BK + slot * 8);
#pragma unroll
        for (int n = 0; n < 4; ++n)
            b[n] = *(const bf16x8*)(bs + (wcol + n * 16 + r16) * BK + slot * 8);
#pragma unroll
        for (int m = 0; m < 4; ++m)
#pragma unroll
            for (int n = 0; n < 4; ++n)
                acc[m][n] = __builtin_amdgcn_mfma_f32_16x16x32_bf16(
                    a[m], b[n], acc[m][n], 0, 0, 0);
        // no trailing barrier / lgkm drain: triple-buffer guarantees the
        // buffer written by STAGE(t+2) was last read at iter t-1, and every
        // wave's passage of the NEXT barrier implies its reads completed.
    }

    // ---- fused epilogue (C/D map: col = lane&15, row = kg*4 + reg) ----
    const float CPOS = -2.8853900817779268f;   //  -2 * log2(e)
    const float CNEG = 57.707801635558536f;    //  40 * log2(e)
    const float DPOS = 1.4426950408889634f;    // -0.5*CPOS
    const float DNEG = -28.853900817779268f;   // -0.5*CNEG

    float ps = 0.f, ns = 0.f;
    unsigned posc = 0, pec = 0;                // wave-uniform (SALU) counters
#pragma unroll
    for (int m = 0; m < 4; ++m) {
        int lab[4] = {rl4[m].x, rl4[m].y, rl4[m].z, rl4[m].w};
#pragma unroll
        for (int j = 0; j < 4; ++j) {
            int myrl = lab[j];
#pragma unroll
            for (int n = 0; n < 4; ++n) {
                float v  = acc[m][n][j];
                bool eq  = (myrl == mycl[n]);
                bool pos = v > 0.f;
                float e  = exp2f(fmaf(v, eq ? CPOS : CNEG, eq ? DPOS : DNEG));
                ps += (pos && eq)  ? e : 0.f;
                ns += (pos && !eq) ? e : 0.f;
                posc += (unsigned)__popcll(__ballot(pos));       // SALU
                pec  += (unsigned)__popcll(__ballot(pos && eq)); // SALU
            }
        }
    }
    // wave reduce (64 lanes) — only the two float sums; counts are uniform
#pragma unroll
    for (int off = 32; off > 0; off >>= 1) {
        ps += __shfl_down(ps, off, 64);
        ns += __shfl_down(ns, off, 64);
    }
    if (lane == 0) {
        double* s = accums + ((((unsigned)blockIdx.x << 2) | (unsigned)wave) & 255u) * 8;
        atomicAdd(s + 0, (double)ps);
        atomicAdd(s + 1, (double)ns);
        atomicAdd((unsigned long long*)(s + 2), (unsigned long long)pec);
        atomicAdd((unsigned long long*)(s + 3), (unsigned long long)(posc - pec));
    }
}

__global__ void finalize_loss(const double* __restrict__ accums,
                              float* __restrict__ out) {
    int lane = threadIdx.x;
    double ps = 0, ns = 0, pc = 0, nc = 0;
#pragma unroll
    for (int s = lane; s < 256; s += 64) {
        ps += accums[s * 8 + 0];
        ns += accums[s * 8 + 1];
        pc += (double)((const unsigned long long*)accums)[s * 8 + 2];
        nc += (double)((const unsigned long long*)accums)[s * 8 + 3];
    }
#pragma unroll
    for (int off = 32; off > 0; off >>= 1) {
        ps += __shfl_down(ps, off, 64);
        ns += __shfl_down(ns, off, 64);
        pc += __shfl_down(pc, off, 64);
        nc += __shfl_down(nc, off, 64);
    }
    if (lane == 0) {
        double pl = (pc > 0.0) ? log1p(ps) / (2.0 * pc)  : 0.0;
        double nl = (nc > 0.0) ? log1p(ns) / (40.0 * nc) : 0.0;
        out[0] = (float)(pl + nl);
    }
}

extern "C" void kernel_launch(void* const* d_in, const int* in_sizes, int n_in,
                              void* d_out, int out_size, void* d_ws, size_t ws_size,
                              hipStream_t stream) {
    (void)in_sizes; (void)n_in; (void)out_size;
    const float* img    = (const float*)d_in[0];
    const float* txt    = (const float*)d_in[1];
    const int*   gt_pre = (const int*)d_in[2];
    const int*   gt_map = (const int*)d_in[3];
    float* out = (float*)d_out;

    const size_t ACC_BYTES = 256 * 8 * sizeof(double);   // 16 KB, 64B slots
    const size_t MAT_BYTES = (size_t)N_IMG * DIMK * 2;   // 4 MB each
    if (ws_size < ACC_BYTES + 2 * MAT_BYTES) return;

    double*         accums = (double*)d_ws;
    unsigned short* Abf = (unsigned short*)((char*)d_ws + ACC_BYTES);
    unsigned short* Bbf = (unsigned short*)((char*)d_ws + ACC_BYTES + MAT_BYTES);

    int nchunks = 2 * N_IMG * (DIMK / 8);
    convert_swz<<<nchunks / 256, 256, 0, stream>>>(img, txt, Abf, Bbf, accums);
    msloss_gemm<<<(N_IMG / BT) * (M_TXT / BT), 256, 0, stream>>>(Abf, Bbf, gt_pre, gt_map, accums);
    finalize_loss<<<1, 64, 0, stream>>>(accums, out);
}

// Round 3
// 75.578 us; speedup vs baseline: 1.1017x; 1.0439x over previous
//
#include <hip/hip_runtime.h>
#include <hip/hip_bf16.h>
#include <math.h>

#define N_IMG 8192
#define M_TXT 8192
#define DIMK  256
#define BT    128    // output tile (BT x BT)
#define BK    32     // K-step

typedef short bf16x8 __attribute__((ext_vector_type(8)));
typedef float f32x4  __attribute__((ext_vector_type(4)));

__device__ inline void gload_lds16(const void* g, void* l) {
    __builtin_amdgcn_global_load_lds(
        (const __attribute__((address_space(1))) unsigned int*)g,
        (__attribute__((address_space(3))) unsigned int*)l,
        16, 0, 0);
}

// RNE fp32 -> bf16 (inputs finite, |x|<=1 -> no NaN handling needed)
__device__ inline unsigned short f2bf(float x) {
    unsigned u = __float_as_uint(x);
    u += 0x7FFFu + ((u >> 16) & 1u);
    return (unsigned short)(u >> 16);
}

// fp32 -> bf16 with the LDS anti-bank-conflict rotation PRE-APPLIED at the
// global level (global_load_lds writes LDS linearly -> permutation must live
// in the source). K-blocks of 32 elems = 4 chunks of 8 bf16; physical chunk j
// of row r holds logical chunk (j - (r>>1)) & 3. Read side uses slot
// (kg + (r16>>1)) & 3 with kg = lane>>4: HW-verified 0 conflicts (slot offset
// MUST vary at lane>>4 granularity; a lane>>5-only variant measured 4.19M
// conflict cycles). Block 0 also zeroes the accumulators.
__global__ void convert_swz(const float* __restrict__ srcA,
                            const float* __restrict__ srcB,
                            unsigned short* __restrict__ dstA,
                            unsigned short* __restrict__ dstB,
                            double* __restrict__ accums) {
    if (blockIdx.x == 0) {
#pragma unroll
        for (int s = 0; s < 8; ++s) accums[threadIdx.x * 8 + s] = 0.0;
    }
    int q = blockIdx.x * blockDim.x + threadIdx.x;
    const int per = N_IMG * (DIMK / 8);
    const float* src; unsigned short* dst; int qq = q;
    if (q < per) { src = srcA; dst = dstA; }
    else         { src = srcB; dst = dstB; qq = q - per; }
    int r  = qq >> 5, jj = qq & 31;          // 32 chunks per row
    int kb = jj >> 2, j = jj & 3;            // K-block (32 elems), chunk in block
    int c  = (j - (r >> 1)) & 3;             // logical chunk stored here
    const float4* s = (const float4*)(src + (size_t)r * DIMK + kb * 32 + c * 8);
    float4 a = s[0], b = s[1];
    uint4 w;
    w.x = (unsigned)f2bf(a.x) | ((unsigned)f2bf(a.y) << 16);
    w.y = (unsigned)f2bf(a.z) | ((unsigned)f2bf(a.w) << 16);
    w.z = (unsigned)f2bf(b.x) | ((unsigned)f2bf(b.y) << 16);
    w.w = (unsigned)f2bf(b.z) | ((unsigned)f2bf(b.w) << 16);
    ((uint4*)dst)[qq] = w;
}

// Fused NT GEMM (img @ text^T) + multi-similarity masked reduction.
// EXACT round-0 proven core: 128x128 tile, 4 waves (2Mx2N), 16x16x32 MFMA,
// BK=32, double-buffered LDS (32 KB), 2 barriers + lgkm drain per K-step
// (the m97 structure; 68.3 us measured, 0 bank conflicts, FETCH 40 MB).
// Changes vs round-0, each counter-separable:
//  - __launch_bounds__(256,4): VGPR 56 + AGPR 64 = 120 <= 128-reg budget for
//    4 waves/SIMD; LDS 4x32=128<=160 KB -> 4th co-resident block for phase
//    diversity (m114 overlap). Watch OccupancyPercent.
//  - epilogue: wave-uniform skip of the exp/fma path when no lane has
//    (pos&&eq) and no lane has v>0.25 (dropped neg terms <= e^-10 each ->
//    final-loss error ~1e-10). Counts exact via ballot+popcount (SALU).
//  - labels preloaded before the K-loop (latency hidden by iter-0 vmcnt(4);
//    in-order vmcnt retirement covers them).
__launch_bounds__(256, 4)
__global__ void msloss_gemm(const unsigned short* __restrict__ Abf,
                            const unsigned short* __restrict__ Bbf,
                            const int* __restrict__ rowLab,
                            const int* __restrict__ colLab,
                            double* __restrict__ accums) {
    __shared__ __align__(16) unsigned short As[2][BT * BK];   // 8 KB each
    __shared__ __align__(16) unsigned short Bs[2][BT * BK];

    int tid  = threadIdx.x;
    int wave = tid >> 6, lane = tid & 63;
    int r16  = lane & 15, kg = lane >> 4;
    int wrow = (wave >> 1) * 64, wcol = (wave & 1) * 64;

    // bijective XCD swizzle (4096 blocks, 8 XCDs); within an XCD consecutive
    // blocks walk J at fixed I -> A-panel L2 reuse.
    int swz = (blockIdx.x & 7) * 512 + (blockIdx.x >> 3);
    int tileRow = (swz >> 6) * BT;
    int tileCol = (swz & 63) * BT;

    // Preload labels (8 VMEM ops, retired by iter-0's vmcnt(4)).
    int tr = tileRow + wrow, tc = tileCol + wcol;
    int4 rl4[4]; int mycl[4];
#pragma unroll
    for (int m = 0; m < 4; ++m)
        rl4[m] = *(const int4*)(rowLab + tr + m * 16 + kg * 4);
#pragma unroll
    for (int n = 0; n < 4; ++n)
        mycl[n] = colLab[tc + n * 16 + r16];

    auto STAGE = [&](int sel, int k0) {
#pragma unroll
        for (int i = 0; i < 2; ++i) {
            int p = wave * 128 + i * 64 + lane;      // chunk id 0..511
            int r = p >> 2, j = p & 3;
            gload_lds16(Abf + (size_t)(tileRow + r) * DIMK + k0 + j * 8,
                        &As[sel][(wave * 128 + i * 64) * 8]);
        }
#pragma unroll
        for (int i = 0; i < 2; ++i) {
            int p = wave * 128 + i * 64 + lane;
            int r = p >> 2, j = p & 3;
            gload_lds16(Bbf + (size_t)(tileCol + r) * DIMK + k0 + j * 8,
                        &Bs[sel][(wave * 128 + i * 64) * 8]);
        }
    };

    f32x4 acc[4][4] = {};

    STAGE(0, 0);

#pragma unroll 1
    for (int t = 0; t < DIMK / BK; ++t) {
        if (t < DIMK / BK - 1) {
            STAGE((t + 1) & 1, (t + 1) * BK);        // 4 loads/lane in flight
            asm volatile("s_waitcnt vmcnt(4)" ::: "memory");  // my stage t done
        } else {
            asm volatile("s_waitcnt vmcnt(0)" ::: "memory");
        }
        __builtin_amdgcn_s_barrier();                // all waves' stage t done
        __builtin_amdgcn_sched_barrier(0);

        const unsigned short* as = As[t & 1];
        const unsigned short* bs = Bs[t & 1];
        int slot = ((r16 >> 1) + kg) & 3;
        bf16x8 a[4], b[4];
#pragma unroll
        for (int m = 0; m < 4; ++m)
            a[m] = *(const bf16x8*)(as + (wrow + m * 16 + r16) * BK + slot * 8);
#pragma unroll
        for (int n = 0; n < 4; ++n)
            b[n] = *(const bf16x8*)(bs + (wcol + n * 16 + r16) * BK + slot * 8);
#pragma unroll
        for (int m = 0; m < 4; ++m)
#pragma unroll
            for (int n = 0; n < 4; ++n)
                acc[m][n] = __builtin_amdgcn_mfma_f32_16x16x32_bf16(
                    a[m], b[n], acc[m][n], 0, 0, 0);

        asm volatile("s_waitcnt lgkmcnt(0)" ::: "memory");   // reads of buf done
        __builtin_amdgcn_sched_barrier(0);
        __builtin_amdgcn_s_barrier();
    }

    // ---- fused epilogue (C/D map: col = lane&15, row = kg*4 + reg) ----
    const float CPOS = -2.8853900817779268f;   //  -2 * log2(e)
    const float CNEG = 57.707801635558536f;    //  40 * log2(e)
    const float DPOS = 1.4426950408889634f;    // -0.5*CPOS
    const float DNEG = -28.853900817779268f;   // -0.5*CNEG
    const float THI  = 0.25f;  // skip thresh: dropped terms <= e^-10 each

    float ps = 0.f, ns = 0.f;
    unsigned posc = 0, pec = 0;                // wave-uniform (SALU) counters
#pragma unroll
    for (int m = 0; m < 4; ++m) {
        int lab[4] = {rl4[m].x, rl4[m].y, rl4[m].z, rl4[m].w};
#pragma unroll
        for (int j = 0; j < 4; ++j) {
            int myrl = lab[j];
#pragma unroll
            for (int n = 0; n < 4; ++n) {
                float v  = acc[m][n][j];
                bool eq  = (myrl == mycl[n]);
                bool pos = v > 0.f;
                unsigned long long bp  = __ballot(pos);
                unsigned long long bpe = bp & __ballot(eq);
                unsigned long long bhi = __ballot(v > THI);
                posc += (unsigned)__popcll(bp);    // SALU
                pec  += (unsigned)__popcll(bpe);   // SALU
                if (__builtin_expect((bool)(bpe | bhi), 0)) {
                    float targ = fmaf(v, eq ? CPOS : CNEG, eq ? DPOS : DNEG);
                    float e    = exp2f(pos ? targ : -100.f);  // !pos -> ~0
                    bool  pe   = pos && eq;
                    ps += pe ? e : 0.f;
                    ns += pe ? 0.f : e;            // !pos lanes add ~0
                }
            }
        }
    }
    // wave reduce (64 lanes) — only the two float sums; counts are uniform
#pragma unroll
    for (int off = 32; off > 0; off >>= 1) {
        ps += __shfl_down(ps, off, 64);
        ns += __shfl_down(ns, off, 64);
    }
    if (lane == 0) {
        double* s = accums + ((((unsigned)blockIdx.x << 2) | (unsigned)wave) & 255u) * 8;
        atomicAdd(s + 0, (double)ps);
        atomicAdd(s + 1, (double)ns);
        atomicAdd((unsigned long long*)(s + 2), (unsigned long long)pec);
        atomicAdd((unsigned long long*)(s + 3), (unsigned long long)(posc - pec));
    }
}

__global__ void finalize_loss(const double* __restrict__ accums,
                              float* __restrict__ out) {
    int lane = threadIdx.x;
    double ps = 0, ns = 0, pc = 0, nc = 0;
#pragma unroll
    for (int s = lane; s < 256; s += 64) {
        ps += accums[s * 8 + 0];
        ns += accums[s * 8 + 1];
        pc += (double)((const unsigned long long*)accums)[s * 8 + 2];
        nc += (double)((const unsigned long long*)accums)[s * 8 + 3];
    }
#pragma unroll
    for (int off = 32; off > 0; off >>= 1) {
        ps += __shfl_down(ps, off, 64);
        ns += __shfl_down(ns, off, 64);
        pc += __shfl_down(pc, off, 64);
        nc += __shfl_down(nc, off, 64);
    }
    if (lane == 0) {
        double pl = (pc > 0.0) ? log1p(ps) / (2.0 * pc)  : 0.0;
        double nl = (nc > 0.0) ? log1p(ns) / (40.0 * nc) : 0.0;
        out[0] = (float)(pl + nl);
    }
}

extern "C" void kernel_launch(void* const* d_in, const int* in_sizes, int n_in,
                              void* d_out, int out_size, void* d_ws, size_t ws_size,
                              hipStream_t stream) {
    (void)in_sizes; (void)n_in; (void)out_size;
    const float* img    = (const float*)d_in[0];
    const float* txt    = (const float*)d_in[1];
    const int*   gt_pre = (const int*)d_in[2];
    const int*   gt_map = (const int*)d_in[3];
    float* out = (float*)d_out;

    const size_t ACC_BYTES = 256 * 8 * sizeof(double);   // 16 KB, 64B slots
    const size_t MAT_BYTES = (size_t)N_IMG * DIMK * 2;   // 4 MB each
    if (ws_size < ACC_BYTES + 2 * MAT_BYTES) return;

    double*         accums = (double*)d_ws;
    unsigned short* Abf = (unsigned short*)((char*)d_ws + ACC_BYTES);
    unsigned short* Bbf = (unsigned short*)((char*)d_ws + ACC_BYTES + MAT_BYTES);

    int nchunks = 2 * N_IMG * (DIMK / 8);
    convert_swz<<<nchunks / 256, 256, 0, stream>>>(img, txt, Abf, Bbf, accums);
    msloss_gemm<<<(N_IMG / BT) * (M_TXT / BT), 256, 0, stream>>>(Abf, Bbf, gt_pre, gt_map, accums);
    finalize_loss<<<1, 64, 0, stream>>>(accums, out);
}